// Round 6
// baseline (533.894 us; speedup 1.0000x reference)
//
#include <hip/hip_runtime.h>

// ---------------------------------------------------------------------------
// EdgeUpdaterFrameDiff: x_down proj -> outer-concat edge bias -> 2-layer MLP
// with relu + residual -> out proj -> LayerNorm.  bf16 MFMA implementation.
//
// R9: 2-blocks-per-CU via LDS diet to exactly 80 KB. Theory: R7/R8 refuted
// LDS-throughput and source-pipelining; the remaining model is phase
// serialization at 1 block/CU (5 barrier phases, nothing overlaps). Diet:
// (1) xd[i] (identical for all 64 rows) no longer staged -- L1 A-frags for
// k<128 and the L2 residual read it from global (L1-cache-hot, uniform);
// (2) xd_j and z in compact [64][128] bf16 regions, h1/s in [64][384],
// all XOR-swizzled (off ^= (row&7)<<4, T2) instead of padded;
// (3) s overwrites h1 in place, sO overlays h1/s -- each guarded by a
// mid-phase __syncthreads. 16384+16384+49152 = 81920 B -> 2 blocks/CU.
// Work split, epilogue C/D mappings, LN: R7 verbatim. No launch_bounds
// min-arg (R5 spill lesson). Canaries: VGPR<=85, WRITE_SIZE==131072.
// ---------------------------------------------------------------------------

using bf16x8 = __attribute__((ext_vector_type(8))) __bf16;
using f32x16 = __attribute__((ext_vector_type(16))) float;

#define OPAD 132            // f32 row stride for 128-wide LN staging overlay

__device__ inline unsigned short f2bf(float f) {
    union { float f; unsigned int u; } v; v.f = f;
    unsigned int r = v.u + 0x7fffu + ((v.u >> 16) & 1u);   // RNE
    return (unsigned short)(r >> 16);
}
__device__ inline float bf2f(unsigned short h) {
    union { unsigned int u; float f; } v; v.u = ((unsigned int)h) << 16;
    return v.f;
}

// --------------- merged prep: xdown (blocks 0..255) + wswz (256..423) ------
// [R8 verbatim — passed]
__global__ void k_prep(const float* __restrict__ x, const float* __restrict__ Wd,
                       const float* __restrict__ bd, unsigned short* __restrict__ xd,
                       const float* __restrict__ W1, const float* __restrict__ W2,
                       const float* __restrict__ Wo,
                       unsigned short* __restrict__ W1s, unsigned short* __restrict__ W2s,
                       unsigned short* __restrict__ Wos) {
    if (blockIdx.x < 256) {
        __shared__ float sx[2][256];
        const int half = threadIdx.x >> 7;     // 0/1 -> row
        const int t = threadIdx.x & 127;       // output col
        const int i = blockIdx.x * 2 + half;   // row 0..511
        if (t < 64) *(float4*)&sx[half][t * 4] = *(const float4*)&x[i * 256 + t * 4];
        __syncthreads();
        const float* wr = &Wd[t * 256];
        const float* xr = sx[half];
        float sum = 0.f;
#pragma unroll 8
        for (int k = 0; k < 256; k += 4) {
            float4 wv = *(const float4*)&wr[k];
            float4 xv = *(const float4*)&xr[k];
            sum += wv.x * xv.x + wv.y * xv.y + wv.z * xv.z + wv.w * xv.w;
        }
        xd[i * 128 + t] = f2bf(sum + bd[t]);
    } else {
        const int b = blockIdx.x - 256;
        const float* W; unsigned short* dst; int c;
        if (b < 72)       { W = W1; dst = W1s; c = b * 256 + threadIdx.x; }
        else if (b < 144) { W = W2; dst = W2s; c = (b - 72) * 256 + threadIdx.x; }
        else              { W = Wo; dst = Wos; c = (b - 144) * 256 + threadIdx.x; }
        int lane = c & 63;
        int ks = (c >> 6) % 24;
        int nt = c / (24 * 64);
        int n = nt * 32 + (lane & 31);
        int k0 = ks * 16 + ((lane >> 5) << 3);
        const float* src = &W[n * 384 + k0];
        unsigned short tmp[8];
#pragma unroll
        for (int j = 0; j < 8; ++j) tmp[j] = f2bf(src[j]);
        *(uint4*)&dst[(size_t)c * 8] = *(const uint4*)tmp;
    }
}

// ------------------------------- main kernel -------------------------------
// LDS map (bytes):
//   sX  @ 0      : xd_j  [64][128] bf16, XOR-swizzled, 16384
//   sZ  @ 16384  : z     [64][128] bf16, XOR-swizzled, 16384
//   sH  @ 32768  : h1->s [64][384] bf16, XOR-swizzled, 49152
//                  (phase D epilogue overlays sO = f32 [64][OPAD] = 33792)
// total 81920 B -> 2 blocks/CU.
__global__ __launch_bounds__(768) void edge_main(
    const float* __restrict__ z, const unsigned short* __restrict__ xd,
    const unsigned short* __restrict__ W1s, const unsigned short* __restrict__ W2s,
    const unsigned short* __restrict__ Wos,
    const float* __restrict__ b1, const float* __restrict__ b2,
    const float* __restrict__ bo, const float* __restrict__ gamma,
    const float* __restrict__ beta, float* __restrict__ out)
{
    extern __shared__ char smem[];
    char* sXb = smem;
    char* sZb = smem + 16384;
    char* sHb = smem + 32768;
    float* sO = (float*)(smem + 32768);

    const int tid = threadIdx.x;
    const int lane = tid & 63;
    const int w = tid >> 6;                   // wave 0..11
    const int i = blockIdx.x >> 3;            // 0..511
    const int j0 = (blockIdx.x & 7) << 6;     // 0..448

    const int arow = lane & 31;
    const int kof = (lane >> 5) << 3;   // 0 or 8
    const int half2 = (lane >> 5) << 2; // 0 or 4 (C/D row offset)

    // R7 work split for L1/L2: row-half + two N-tiles per wave
    const int mt  = w & 1;
    const int ng  = w >> 1;             // 0..5 -> N-tiles ng and ng+6
    const int rbase = mt << 5;
    const int row = rbase + arow;       // A-row for L1/L2
    const int rswz = (row & 7) << 4;    // XOR swizzle for this row

    // ---- stage X = xd_j rows (uint4, swizzled dest) ----
    for (int c = tid; c < 64 * 16; c += 768) {
        int r = c >> 4, cb = (c & 15) << 4;               // byte-in-row 0..240
        *(uint4*)(sXb + ((r * 256 + cb) ^ ((r & 7) << 4))) =
            *(const uint4*)&xd[(j0 + r) * 128 + (cb >> 1)];
    }
    // ---- stage Z = bf16(z) (ushort4, swizzled dest) ----
    for (int c = tid; c < 64 * 32; c += 768) {
        int r = c >> 5, cc = (c & 31) << 2;               // f32 col 0..124
        float4 v = *(const float4*)&z[((size_t)((i << 9) + j0 + r) << 7) + cc];
        ushort4 o;
        o.x = f2bf(v.x); o.y = f2bf(v.y); o.z = f2bf(v.z); o.w = f2bf(v.w);
        *(ushort4*)(sZb + ((r * 256 + (cc << 1)) ^ ((r & 7) << 4))) = o;
    }
    __syncthreads();

    const int colA = ng * 32 + arow;          // in [0,192)
    const int colB = colA + 192;              // in [192,384)

    // ===== layer 1: h1 = relu(z_in @ W1^T + b1) =====
    // A-frag source by k-range: k<128 global xd_i; k<256 X; else Z.
    {
        f32x16 acc0 = {}, acc1 = {};
#pragma unroll
        for (int ks = 0; ks < 24; ++ks) {
            const int k = ks * 16 + kof;
            bf16x8 a;
            if (ks < 8)
                a = *(const bf16x8*)&xd[i * 128 + k];
            else if (ks < 16)
                a = *(const bf16x8*)(sXb + ((row * 256 + (k - 128) * 2) ^ rswz));
            else
                a = *(const bf16x8*)(sZb + ((row * 256 + (k - 256) * 2) ^ rswz));
            bf16x8 b0  = *(const bf16x8*)&W1s[(size_t)(((ng    ) * 24 + ks) * 64 + lane) * 8];
            bf16x8 bb1 = *(const bf16x8*)&W1s[(size_t)(((ng + 6) * 24 + ks) * 64 + lane) * 8];
            acc0 = __builtin_amdgcn_mfma_f32_32x32x16_bf16(a, b0,  acc0, 0, 0, 0);
            acc1 = __builtin_amdgcn_mfma_f32_32x32x16_bf16(a, bb1, acc1, 0, 0, 0);
        }
        const float biasA = b1[colA];
        const float biasB = b1[colB];
#pragma unroll
        for (int rg = 0; rg < 16; ++rg) {
            int rr = rbase + half2 + (rg & 3) + ((rg >> 2) << 3);
            int rsw = (rr & 7) << 4;
            float v0 = acc0[rg] + biasA; v0 = v0 > 0.f ? v0 : 0.f;
            float v1 = acc1[rg] + biasB; v1 = v1 > 0.f ? v1 : 0.f;
            *(unsigned short*)(sHb + ((rr * 768 + colA * 2) ^ rsw)) = f2bf(v0);
            *(unsigned short*)(sHb + ((rr * 768 + colB * 2) ^ rsw)) = f2bf(v1);
        }
    }
    __syncthreads();

    // ===== layer 2: s = relu(h1 @ W2^T + b2) + z_in, in place over h1 =====
    {
        f32x16 acc0 = {}, acc1 = {};
#pragma unroll
        for (int ks = 0; ks < 24; ++ks) {
            const int k = ks * 16 + kof;
            bf16x8 a  = *(const bf16x8*)(sHb + ((row * 768 + k * 2) ^ rswz));
            bf16x8 b0  = *(const bf16x8*)&W2s[(size_t)(((ng    ) * 24 + ks) * 64 + lane) * 8];
            bf16x8 bb1 = *(const bf16x8*)&W2s[(size_t)(((ng + 6) * 24 + ks) * 64 + lane) * 8];
            acc0 = __builtin_amdgcn_mfma_f32_32x32x16_bf16(a, b0,  acc0, 0, 0, 0);
            acc1 = __builtin_amdgcn_mfma_f32_32x32x16_bf16(a, bb1, acc1, 0, 0, 0);
        }
        __syncthreads();   // all h1 reads complete before s overwrites it

        const float biasA = b2[colA];
        const float biasB = b2[colB];
        // residual sources (wave-uniform): colA<128 -> global xd_i; else X.
        // colB<256 -> X; else Z.
        const bool aGlob = (ng <= 3);
        float resAg = 0.f;
        if (aGlob) resAg = bf2f(xd[i * 128 + colA]);   // row-independent
#pragma unroll
        for (int rg = 0; rg < 16; ++rg) {
            int rr = rbase + half2 + (rg & 3) + ((rg >> 2) << 3);
            int rsw = (rr & 7) << 4;
            float v0 = acc0[rg] + biasA; v0 = v0 > 0.f ? v0 : 0.f;
            float v1 = acc1[rg] + biasB; v1 = v1 > 0.f ? v1 : 0.f;
            float r0 = aGlob ? resAg
                 : bf2f(*(const unsigned short*)(sXb + ((rr * 256 + (colA - 128) * 2) ^ rsw)));
            float r1 = (ng <= 1)
                 ? bf2f(*(const unsigned short*)(sXb + ((rr * 256 + (colB - 128) * 2) ^ rsw)))
                 : bf2f(*(const unsigned short*)(sZb + ((rr * 256 + (colB - 256) * 2) ^ rsw)));
            *(unsigned short*)(sHb + ((rr * 768 + colA * 2) ^ rsw)) = f2bf(v0 + r0);
            *(unsigned short*)(sHb + ((rr * 768 + colB * 2) ^ rsw)) = f2bf(v1 + r1);
        }
    }
    __syncthreads();

    // ===== layer 3: out = s @ Wo^T + bo; waves 0..7 -> (mt3,nt3) units =====
    f32x16 acc3 = {};
    const int mt3 = w >> 2;
    const int nt3 = w & 3;
    if (w < 8) {
        const int row3 = mt3 * 32 + arow;
        const int r3sw = (row3 & 7) << 4;
#pragma unroll
        for (int ks = 0; ks < 24; ++ks) {
            const int k = ks * 16 + kof;
            bf16x8 a = *(const bf16x8*)(sHb + ((row3 * 768 + k * 2) ^ r3sw));
            bf16x8 b = *(const bf16x8*)&Wos[(size_t)((nt3 * 24 + ks) * 64 + lane) * 8];
            acc3 = __builtin_amdgcn_mfma_f32_32x32x16_bf16(a, b, acc3, 0, 0, 0);
        }
    }
    __syncthreads();   // all s reads complete before sO overlays the region
    if (w < 8) {
        int col = nt3 * 32 + arow;
        float bias = bo[col];
#pragma unroll
        for (int rg = 0; rg < 16; ++rg) {
            int rr = mt3 * 32 + half2 + (rg & 3) + ((rg >> 2) << 3);
            sO[rr * OPAD + col] = acc3[rg] + bias;
        }
    }
    __syncthreads();

    // ===================== LayerNorm + store  [R7 verbatim] =================
    if (tid < 256) {
        const int r = tid >> 2;       // row 0..63
        const int q = tid & 3;        // quarter
        float s = 0.f, ss = 0.f;
#pragma unroll
        for (int ii = 0; ii < 32; ++ii) {
            float v = sO[r * OPAD + q + (ii << 2)];
            s += v; ss += v * v;
        }
        s += __shfl_xor(s, 1);  ss += __shfl_xor(ss, 1);
        s += __shfl_xor(s, 2);  ss += __shfl_xor(ss, 2);
        const float mean = s * (1.f / 128.f);
        const float var = ss * (1.f / 128.f) - mean * mean;
        const float rstd = rsqrtf(var + 1e-5f);
        float* po = &out[((size_t)((i << 9) + j0 + r)) << 7];
#pragma unroll
        for (int ii = 0; ii < 8; ++ii) {
            int c0 = q * 32 + (ii << 2);
            float4 v = *(const float4*)&sO[r * OPAD + c0];
            float4 g = *(const float4*)&gamma[c0];
            float4 bb = *(const float4*)&beta[c0];
            float4 o;
            o.x = (v.x - mean) * rstd * g.x + bb.x;
            o.y = (v.y - mean) * rstd * g.y + bb.y;
            o.z = (v.z - mean) * rstd * g.z + bb.z;
            o.w = (v.w - mean) * rstd * g.w + bb.w;
            *(float4*)&po[c0] = o;
        }
    }
}

extern "C" void kernel_launch(void* const* d_in, const int* in_sizes, int n_in,
                              void* d_out, int out_size, void* d_ws, size_t ws_size,
                              hipStream_t stream) {
    const float* x     = (const float*)d_in[0];
    const float* z     = (const float*)d_in[1];
    const float* Wd    = (const float*)d_in[2];
    const float* bd    = (const float*)d_in[3];
    const float* W1    = (const float*)d_in[4];
    const float* b1    = (const float*)d_in[5];
    const float* W2    = (const float*)d_in[6];
    const float* b2    = (const float*)d_in[7];
    const float* Wo    = (const float*)d_in[8];
    const float* bo    = (const float*)d_in[9];
    const float* gamma = (const float*)d_in[10];
    const float* beta  = (const float*)d_in[11];
    float* out = (float*)d_out;

    unsigned short* xd  = (unsigned short*)d_ws;                       // 512*128*2   = 131072
    unsigned short* W1s = (unsigned short*)((char*)d_ws + 131072);     // 294912
    unsigned short* W2s = (unsigned short*)((char*)d_ws + 425984);     // 294912
    unsigned short* Wos = (unsigned short*)((char*)d_ws + 720896);     // 98304

    hipLaunchKernelGGL(k_prep, dim3(424), dim3(256), 0, stream,
                       x, Wd, bd, xd, W1, W2, Wo, W1s, W2s, Wos);

    const size_t smem = 81920;   // sX(16K) + sZ(16K) + sH/sO(48K) = 80 KB -> 2 blocks/CU
    hipLaunchKernelGGL(edge_main, dim3(4096), dim3(768), smem, stream,
                       z, xd, W1s, W2s, Wos, b1, b2, bo, gamma, beta, out);
}